// Round 12
// baseline (162.515 us; speedup 1.0000x reference)
//
#include <hip/hip_runtime.h>

// x (4096, 2, 1024) fp32.  P_i = x[i,0,:], A_j = x[i,1,:]
// out[0] = 1.0 exactly; out[1] = prec1 = 100*mean(argmax_j sim[i,j] == i)
// argmax_j sim[i,j] == argmax_j dot(P_i,A_j)*inv_norm(A_j).
// R24: kill the frag round-trip. conv wrote 16MB that the GEMM re-read
// (24.8MB FETCH). The GEMM now stages DIRECTLY from x: per phase, issue
// 2x(float4x2) fp32 loads at phase start; after the MFMA burst convert
// (same f2bf -> bitwise-identical frags) and ds_write_b128 into the SAME
// LDS slots gload_lds used -> ds_read/MFMA/epilogue path untouched (R15
// structure, proven 48.5-49.2us). Anchor norms fold in free: A values pass
// through regs, each block accumulates its own 256 col sums (8 FMA/phase),
// shfl_xor(32) combine, LDS-resident -> no sums buffer/atomics. Tile-entry
// vmcnt(0) becomes lgkmcnt(0) (drains ds_writes before dbuf flip; barrier
// publishes cross-wave). Two GPU ops total: memset(33KB) + 1 kernel.
// Frag map (R4/R9/R11-verified): LDS slot (kh_l,fb=wave,lane) holds
// row = fb*32+(lane&31), k = kh*16+(lane>>5)*8..+8.

#define NROWS 4096
#define DDIM  1024
#define XSTR  2048

typedef unsigned int u32;
typedef unsigned long long u64;
typedef __attribute__((ext_vector_type(8))) short bf16x8;
typedef __attribute__((ext_vector_type(8))) unsigned short u16x8;
typedef __attribute__((ext_vector_type(16))) float f32x16;

__device__ __forceinline__ unsigned int fkey(float f) {
    unsigned int u = __float_as_uint(f);
    return (u & 0x80000000u) ? ~u : (u | 0x80000000u);
}

__device__ __forceinline__ u64 shfl_xor_u64(u64 v, int m) {
    unsigned int lo = (unsigned int)v;
    unsigned int hi = (unsigned int)(v >> 32);
    lo = __shfl_xor(lo, m, 64);
    hi = __shfl_xor(hi, m, 64);
    return ((u64)hi << 32) | lo;
}

__device__ __forceinline__ unsigned short f2bf(float f) {
    unsigned u = __float_as_uint(f);
    return (unsigned short)((u + 0x7FFFu + ((u >> 16) & 1u)) >> 16);
}

// Workspace layout (bytes): packed argmax + done flag only.
#define PCK_OFF  0u
#define DONE_OFF 32768u
#define WS_NEED  32832u

// ---- single fused kernel: stage-from-x + norms + MFMA GEMM + argmax ----
// 256x256 block tile, 8 waves (4m x 2n) of 64x128. Grid 256, XCD-swizzled.
// LDS per buffer (64KB): [P: kh_l*8KB + fb*1KB] [A: +32KB, same]; x2 dbuf.
// Wave w stages fb=w for both P and A: per phase 4 fp32x4 loads -> cvt ->
// 2 ds_write_b128 (after MFMA), + 8 square-FMAs for the A norm sum.
__global__ __launch_bounds__(512, 2) void mfma_gemm_argmax(const float* __restrict__ x,
                                                           u64* __restrict__ packed,
                                                           unsigned int* __restrict__ done,
                                                           float* __restrict__ out) {
    __shared__ __align__(16) unsigned int lds[32768];  // 128 KB, 2 x 64KB buffers
    __shared__ float sums_s[256];
    __shared__ unsigned int lastflag;
    __shared__ int cnt[8];

    const int bid = blockIdx.x;
    const int xcd = bid & 7;
    const int slt = bid >> 3;                       // 0..31
    const int rblk = (xcd >> 1) * 4 + (slt >> 3);   // 0..15
    const int cblk = (xcd & 1) * 8 + (slt & 7);     // 0..15
    const int r0 = rblk * 256;
    const int c0 = cblk * 256;

    const int wave = threadIdx.x >> 6;  // 0..7
    const int lane = threadIdx.x & 63;
    const int l31 = lane & 31;
    const int lh = lane >> 5;
    const int wm = wave & 3;   // m-quarter: rows wm*64..+63
    const int wn = wave >> 2;  // n-half:    cols wn*128..+127

    // direct-from-x staging pointers (chunk kh -> +kh*16 floats)
    const int prow = (rblk * 8 + wave) * 32 + l31;
    const int arow = (cblk * 8 + wave) * 32 + l31;
    const float* gPx = x + (size_t)prow * XSTR + lh * 8;
    const float* gAx = x + (size_t)arow * XSTR + DDIM + lh * 8;

    f32x16 zero16 = {0.f,0.f,0.f,0.f,0.f,0.f,0.f,0.f,0.f,0.f,0.f,0.f,0.f,0.f,0.f,0.f};
    f32x16 acc[2][4];
#pragma unroll
    for (int i = 0; i < 2; ++i)
#pragma unroll
        for (int j = 0; j < 4; ++j) acc[i][j] = zero16;

    float sq = 0.0f;   // running sum of squares of my A elements

    // load chunk kh into regs
#define LOADCH(kh, pv0, pv1, av0, av1)                                                  \
    {                                                                                   \
        const float* pp_ = gPx + (kh) * 16;                                             \
        const float* aa_ = gAx + (kh) * 16;                                             \
        pv0 = *(const float4*)(pp_);  pv1 = *(const float4*)(pp_ + 4);                  \
        av0 = *(const float4*)(aa_);  av1 = *(const float4*)(aa_ + 4);                  \
    }

    // convert + write chunk to LDS buffer slot, accumulate A squares
#define WRITECH(bb, kh_l, pv0, pv1, av0, av1)                                           \
    {                                                                                   \
        u16x8 pc_, ac_;                                                                 \
        pc_[0] = f2bf(pv0.x); pc_[1] = f2bf(pv0.y); pc_[2] = f2bf(pv0.z); pc_[3] = f2bf(pv0.w); \
        pc_[4] = f2bf(pv1.x); pc_[5] = f2bf(pv1.y); pc_[6] = f2bf(pv1.z); pc_[7] = f2bf(pv1.w); \
        ac_[0] = f2bf(av0.x); ac_[1] = f2bf(av0.y); ac_[2] = f2bf(av0.z); ac_[3] = f2bf(av0.w); \
        ac_[4] = f2bf(av1.x); ac_[5] = f2bf(av1.y); ac_[6] = f2bf(av1.z); ac_[7] = f2bf(av1.w); \
        *(u16x8*)&lds[(bb) + (kh_l) * 2048 + wave * 256 + lane * 4] = pc_;              \
        *(u16x8*)&lds[(bb) + 8192 + (kh_l) * 2048 + wave * 256 + lane * 4] = ac_;       \
        sq += av0.x * av0.x + av0.y * av0.y + av0.z * av0.z + av0.w * av0.w             \
            + av1.x * av1.x + av1.y * av1.y + av1.z * av1.z + av1.w * av1.w;            \
    }

    // ---- prologue: stage tile 0 (kh 0..3) into buffer 0 ----
#pragma unroll
    for (int kh_l = 0; kh_l < 4; ++kh_l) {
        float4 pv0, pv1, av0, av1;
        LOADCH(kh_l, pv0, pv1, av0, av1)
        WRITECH(0, kh_l, pv0, pv1, av0, av1)
    }

    // ---- K loop: 16 tiles of BK=64 (4 kh phases each), R15 structure ----
    for (int t = 0; t < 16; ++t) {
        const int cb = t & 1;
        const int nbuf = (cb ^ 1) * 16384;
        const int cbuf = cb * 16384;

        // drain my ds_writes; barrier publishes all waves' writes of tile t
        asm volatile("s_waitcnt lgkmcnt(0)" ::: "memory");
        __builtin_amdgcn_s_barrier();
        __builtin_amdgcn_sched_barrier(0);

#pragma unroll
        for (int kh_l = 0; kh_l < 4; ++kh_l) {
            // issue next-tile fp32 loads early (consumed after the MFMAs)
            float4 pv0, pv1, av0, av1;
            if (t + 1 < 16) LOADCH((t + 1) * 4 + kh_l, pv0, pv1, av0, av1)

            // ds_read this phase's 6 fragments (linear, conflict-free)
            const u32* bp = &lds[cbuf + kh_l * 2048 + (wm * 2) * 256 + lane * 4];
            bf16x8 f_p0 = *(const bf16x8*)(bp);
            bf16x8 f_p1 = *(const bf16x8*)(bp + 256);
            const u32* ba = &lds[cbuf + 8192 + kh_l * 2048 + (wn * 4) * 256 + lane * 4];
            bf16x8 f_a0 = *(const bf16x8*)(ba);
            bf16x8 f_a1 = *(const bf16x8*)(ba + 256);
            bf16x8 f_a2 = *(const bf16x8*)(ba + 512);
            bf16x8 f_a3 = *(const bf16x8*)(ba + 768);

            __builtin_amdgcn_s_barrier();
            asm volatile("s_waitcnt lgkmcnt(0)" ::: "memory");
            __builtin_amdgcn_sched_barrier(0);
            __builtin_amdgcn_s_setprio(1);
            acc[0][0] = __builtin_amdgcn_mfma_f32_32x32x16_bf16(f_p0, f_a0, acc[0][0], 0, 0, 0);
            acc[0][1] = __builtin_amdgcn_mfma_f32_32x32x16_bf16(f_p0, f_a1, acc[0][1], 0, 0, 0);
            acc[0][2] = __builtin_amdgcn_mfma_f32_32x32x16_bf16(f_p0, f_a2, acc[0][2], 0, 0, 0);
            acc[0][3] = __builtin_amdgcn_mfma_f32_32x32x16_bf16(f_p0, f_a3, acc[0][3], 0, 0, 0);
            acc[1][0] = __builtin_amdgcn_mfma_f32_32x32x16_bf16(f_p1, f_a0, acc[1][0], 0, 0, 0);
            acc[1][1] = __builtin_amdgcn_mfma_f32_32x32x16_bf16(f_p1, f_a1, acc[1][1], 0, 0, 0);
            acc[1][2] = __builtin_amdgcn_mfma_f32_32x32x16_bf16(f_p1, f_a2, acc[1][2], 0, 0, 0);
            acc[1][3] = __builtin_amdgcn_mfma_f32_32x32x16_bf16(f_p1, f_a3, acc[1][3], 0, 0, 0);
            __builtin_amdgcn_s_setprio(0);

            // convert + stage into nbuf (loads have had the MFMA burst to land)
            if (t + 1 < 16) WRITECH(nbuf, kh_l, pv0, pv1, av0, av1)

            __builtin_amdgcn_s_barrier();
        }
    }
#undef LOADCH
#undef WRITECH

    // ---- fold per-thread A square sums -> per-column sums in LDS ----
    {
        float st = sq + __shfl_xor(sq, 32, 64);
        if (lane < 32) sums_s[wave * 32 + lane] = st;
    }
    __syncthreads();

    // ---- epilogue: ian = 1/sqrt(sum), packed argmax ----
    float ian[4];
#pragma unroll
    for (int nt = 0; nt < 4; ++nt) ian[nt] = 1.0f / sqrtf(sums_s[wn * 128 + nt * 32 + l31]);

    // 32x32 C/D layout (m74/m101): col = lane&31, row = (reg&3)+8*(reg>>2)+4*(lane>>5)
#pragma unroll
    for (int mt = 0; mt < 2; ++mt)
#pragma unroll
        for (int reg = 0; reg < 16; ++reg) {
            const int row = r0 + wm * 64 + mt * 32 + (reg & 3) + 8 * (reg >> 2) + 4 * lh;
            u64 best = 0ULL;
#pragma unroll
            for (int nt = 0; nt < 4; ++nt) {
                const int col = c0 + wn * 128 + nt * 32 + l31;
                const float v = acc[mt][nt][reg] * ian[nt];
                const u64 p = ((u64)fkey(v) << 32) | (unsigned int)(~col);
                best = best > p ? best : p;
            }
#pragma unroll
            for (int m = 1; m <= 16; m <<= 1) {
                const u64 o = shfl_xor_u64(best, m);
                best = best > o ? best : o;
            }
            if (l31 == 0) atomicMax(&packed[row], best);
        }

    // ---- fused finalize: last block counts and writes out ----
    __syncthreads();
    if (threadIdx.x == 0) {
        __threadfence();  // publish this block's atomicMax results
        unsigned int old = atomicAdd(done, 1u);
        lastflag = (old == 255u) ? 1u : 0u;
    }
    __syncthreads();
    if (lastflag) {
        int c = 0;
        for (int r = threadIdx.x; r < NROWS; r += 512) {
            u64 v = atomicAdd(&packed[r], 0ULL);  // device-coherent read
            unsigned int col = ~(unsigned int)(v & 0xFFFFFFFFULL);
            c += (col == (unsigned int)r) ? 1 : 0;
        }
#pragma unroll
        for (int off = 32; off > 0; off >>= 1) c += __shfl_down(c, off, 64);
        if ((threadIdx.x & 63) == 0) cnt[threadIdx.x >> 6] = c;
        __syncthreads();
        if (threadIdx.x == 0) {
            int tot = 0;
#pragma unroll
            for (int w = 0; w < 8; ++w) tot += cnt[w];
            out[0] = 1.0f;  // exp(temploss - stop_gradient(temploss)) == 1 exactly
            out[1] = 100.0f * (float)tot / (float)NROWS;
        }
    }
}

// ---------------- fallback fp32 path (proven R1) ----------------
__global__ __launch_bounds__(256) void norms_kernel(const float* __restrict__ x,
                                                    float* __restrict__ inv_an,
                                                    u64* __restrict__ packed) {
    int gid  = blockIdx.x * 256 + threadIdx.x;
    int j    = gid >> 6;
    int lane = threadIdx.x & 63;
    if (gid < NROWS) packed[gid] = 0ULL;
    const float4* a = (const float4*)(x + (size_t)j * XSTR + DDIM);
    float s = 0.0f;
#pragma unroll
    for (int i = 0; i < 4; ++i) {
        float4 v = a[lane + i * 64];
        s += v.x * v.x + v.y * v.y + v.z * v.z + v.w * v.w;
    }
#pragma unroll
    for (int off = 32; off > 0; off >>= 1) s += __shfl_down(s, off, 64);
    if (lane == 0) inv_an[j] = 1.0f / sqrtf(s);
}

__global__ __launch_bounds__(256) void gemm_argmax_kernel(const float* __restrict__ x,
                                                          const float* __restrict__ inv_an,
                                                          u64* __restrict__ packed) {
    __shared__ __align__(16) float Pt[16][128];
    __shared__ __align__(16) float At[16][128];
    const int r0 = blockIdx.x * 128;
    const int c0 = blockIdx.y * 128;
    const int t = threadIdx.x;
    const int tx = t & 15;
    const int ty = t >> 4;
    const int srow = t >> 1;
    const int skq = (t & 1) * 8;
    float acc[8][8];
#pragma unroll
    for (int r = 0; r < 8; ++r)
#pragma unroll
        for (int c = 0; c < 8; ++c) acc[r][c] = 0.0f;
    const float* gp = x + (size_t)(r0 + srow) * XSTR + skq;
    const float* ga = x + (size_t)(c0 + srow) * XSTR + DDIM + skq;
    for (int k0 = 0; k0 < DDIM; k0 += 16) {
        __syncthreads();
        float4 p0 = *(const float4*)(gp + k0);
        float4 p1 = *(const float4*)(gp + k0 + 4);
        float4 a0 = *(const float4*)(ga + k0);
        float4 a1 = *(const float4*)(ga + k0 + 4);
        Pt[skq + 0][srow] = p0.x; Pt[skq + 1][srow] = p0.y;
        Pt[skq + 2][srow] = p0.z; Pt[skq + 3][srow] = p0.w;
        Pt[skq + 4][srow] = p1.x; Pt[skq + 5][srow] = p1.y;
        Pt[skq + 6][srow] = p1.z; Pt[skq + 7][srow] = p1.w;
        At[skq + 0][srow] = a0.x; At[skq + 1][srow] = a0.y;
        At[skq + 2][srow] = a0.z; At[skq + 3][srow] = a0.w;
        At[skq + 4][srow] = a1.x; At[skq + 5][srow] = a1.y;
        At[skq + 6][srow] = a1.z; At[skq + 7][srow] = a1.w;
        __syncthreads();
#pragma unroll
        for (int kk = 0; kk < 16; ++kk) {
            float pr[8], ar[8];
            *(float4*)&pr[0] = *(const float4*)&Pt[kk][ty * 8];
            *(float4*)&pr[4] = *(const float4*)&Pt[kk][ty * 8 + 4];
            *(float4*)&ar[0] = *(const float4*)&At[kk][tx * 8];
            *(float4*)&ar[4] = *(const float4*)&At[kk][tx * 8 + 4];
#pragma unroll
            for (int r = 0; r < 8; ++r)
#pragma unroll
                for (int c = 0; c < 8; ++c) acc[r][c] += pr[r] * ar[c];
        }
    }
    float ian[8];
#pragma unroll
    for (int c = 0; c < 8; ++c) ian[c] = inv_an[c0 + tx * 8 + c];
#pragma unroll
    for (int r = 0; r < 8; ++r) {
        int row = r0 + ty * 8 + r;
        u64 best = 0ULL;
#pragma unroll
        for (int c = 0; c < 8; ++c) {
            int col = c0 + tx * 8 + c;
            float v = acc[r][c] * ian[c];
            u64 p = ((u64)fkey(v) << 32) | (unsigned int)(~col);
            best = best > p ? best : p;
        }
#pragma unroll
        for (int m = 1; m <= 8; m <<= 1) {
            u64 o = shfl_xor_u64(best, m);
            best = best > o ? best : o;
        }
        if (tx == 0) atomicMax(&packed[row], best);
    }
}

__global__ __launch_bounds__(256) void finalize_kernel(const u64* __restrict__ packed,
                                                       float* __restrict__ out) {
    __shared__ int cnt_s;
    int t = threadIdx.x;
    if (t == 0) cnt_s = 0;
    __syncthreads();
    int c = 0;
    for (int r = t; r < NROWS; r += 256) {
        unsigned int col = ~(unsigned int)(packed[r] & 0xFFFFFFFFULL);
        c += (col == (unsigned int)r) ? 1 : 0;
    }
#pragma unroll
    for (int off = 32; off > 0; off >>= 1) c += __shfl_down(c, off, 64);
    if ((t & 63) == 0) atomicAdd(&cnt_s, c);
    __syncthreads();
    if (t == 0) {
        out[0] = 1.0f;
        out[1] = 100.0f * (float)cnt_s / (float)NROWS;
    }
}

extern "C" void kernel_launch(void* const* d_in, const int* in_sizes, int n_in,
                              void* d_out, int out_size, void* d_ws, size_t ws_size,
                              hipStream_t stream) {
    (void)in_sizes; (void)n_in; (void)out_size;
    const float* x = (const float*)d_in[0];
    float* out = (float*)d_out;

    if (ws_size >= (size_t)WS_NEED) {
        char* ws = (char*)d_ws;
        u64* packed = (u64*)(ws + PCK_OFF);
        unsigned int* done = (unsigned int*)(ws + DONE_OFF);

        hipMemsetAsync(ws, 0, (size_t)WS_NEED, stream);
        mfma_gemm_argmax<<<256, 512, 0, stream>>>(x, packed, done, out);
    } else {
        float* inv_an = (float*)d_ws;
        u64* packed = (u64*)((char*)d_ws + NROWS * sizeof(float));
        norms_kernel<<<NROWS / 4, 256, 0, stream>>>(x, inv_an, packed);
        dim3 grid(NROWS / 128, NROWS / 128);
        gemm_argmax_kernel<<<grid, 256, 0, stream>>>(x, inv_an, packed);
        finalize_kernel<<<1, 256, 0, stream>>>(packed, out);
    }
}

// Round 13
// 120.851 us; speedup vs baseline: 1.3448x; 1.3448x over previous
//
#include <hip/hip_runtime.h>

// x (4096, 2, 1024) fp32.  P_i = x[i,0,:], A_j = x[i,1,:]
// out[0] = 1.0 exactly; out[1] = prec1 = 100*mean(argmax_j sim[i,j] == i)
// argmax_j sim[i,j] == argmax_j dot(P_i,A_j)*inv_norm(A_j).
// R25 = R23 restored (best-known, 122.2us). R24's direct-from-x staging
// regressed 2.3x (FETCH 24.8->49.4MB: 64B-segment strided panel reads at
// 1 blk/CU; staging VALU+ds_write serialized into phases) -> the frag
// materialization round-trip is CHEAPER than inlining it. Session summary:
// 8 GEMM schedules all plateau at 22-27% MfmaUtil (best: R15 fine-barrier
// 48.5-49.2us); coop fusion -2.5x; prep: conv+norms fusion +0.5us (kept).
// Budget: ~58-60us fixed harness overhead + 49 GEMM + 13 conv + 1 memset.
// Frag-order map (R4/R9/R11-verified): block fb region = 64KB at fb*65536;
// byte = kh*1024 + lane*16 -> (row = fb*32 + (lane&31), k = kh*16+(lane>>5)*8..+8).

#define NROWS 4096
#define DDIM  1024
#define XSTR  2048

typedef unsigned int u32;
typedef unsigned long long u64;
typedef __attribute__((ext_vector_type(8))) short bf16x8;
typedef __attribute__((ext_vector_type(8))) unsigned short u16x8;
typedef __attribute__((ext_vector_type(16))) float f32x16;

__device__ __forceinline__ unsigned int fkey(float f) {
    unsigned int u = __float_as_uint(f);
    return (u & 0x80000000u) ? ~u : (u | 0x80000000u);
}

__device__ __forceinline__ u64 shfl_xor_u64(u64 v, int m) {
    unsigned int lo = (unsigned int)v;
    unsigned int hi = (unsigned int)(v >> 32);
    lo = __shfl_xor(lo, m, 64);
    hi = __shfl_xor(hi, m, 64);
    return ((u64)hi << 32) | lo;
}

__device__ __forceinline__ unsigned short f2bf(float f) {
    unsigned u = __float_as_uint(f);
    return (unsigned short)((u + 0x7FFFu + ((u >> 16) & 1u)) >> 16);
}

// Workspace layout (bytes):
#define PF_OFF   0u
#define AF_OFF   8388608u
#define SUM_OFF  16777216u   // 4096 f32 row sum-of-squares (memset to 0)
#define PCK_OFF  16793600u
#define DONE_OFF 16826368u
#define WS_NEED  16826432u
// memset region: [SUM_OFF, WS_NEED) = sums + packed + done
#define ZERO_BYTES (WS_NEED - SUM_OFF)

// ---- prep: fp32 -> bf16 fragment conversion + fused anchor norm sums ----
// One thread per 16B chunk: cid = fb*4096 + kh*64 + lane (proven bit-exact
// frag output). Each thread also squares its 8 A-cols; deterministic block
// reduce then one atomicAdd per row per block (16 contributors/row).
__global__ __launch_bounds__(256) void conv_kernel(const float* __restrict__ x,
                                                   unsigned short* __restrict__ Pf,
                                                   unsigned short* __restrict__ Af,
                                                   float* __restrict__ sums) {
    __shared__ float rsum[256];
    const int t    = threadIdx.x;
    const int cid  = blockIdx.x * 256 + t;
    const int lane = cid & 63;
    const int kh   = (cid >> 6) & 63;
    const int fb   = cid >> 12;            // constant per block (16 blocks/fb)
    const int row  = fb * 32 + (lane & 31);
    const int col  = kh * 16 + (lane >> 5) * 8;

    const float* px = x + (size_t)row * XSTR + col;
    float4 p0 = *(const float4*)(px);
    float4 p1 = *(const float4*)(px + 4);
    float4 a0 = *(const float4*)(px + DDIM);
    float4 a1 = *(const float4*)(px + DDIM + 4);

    u16x8 pv, av;
    pv[0] = f2bf(p0.x); pv[1] = f2bf(p0.y); pv[2] = f2bf(p0.z); pv[3] = f2bf(p0.w);
    pv[4] = f2bf(p1.x); pv[5] = f2bf(p1.y); pv[6] = f2bf(p1.z); pv[7] = f2bf(p1.w);
    av[0] = f2bf(a0.x); av[1] = f2bf(a0.y); av[2] = f2bf(a0.z); av[3] = f2bf(a0.w);
    av[4] = f2bf(a1.x); av[5] = f2bf(a1.y); av[6] = f2bf(a1.z); av[7] = f2bf(a1.w);

    *(u16x8*)(Pf + (size_t)cid * 8) = pv;
    *(u16x8*)(Af + (size_t)cid * 8) = av;

    float s = a0.x * a0.x + a0.y * a0.y + a0.z * a0.z + a0.w * a0.w
            + a1.x * a1.x + a1.y * a1.y + a1.z * a1.z + a1.w * a1.w;
    rsum[t] = s;
    __syncthreads();
    if (t < 32) {
        float tot = 0.0f;
#pragma unroll
        for (int w = 0; w < 8; ++w) tot += rsum[t + 32 * w];
        atomicAdd(&sums[fb * 32 + t], tot);   // 16 blocks contribute per row
    }
}

// ---- MFMA GEMM + argmax + fused finalize (R15 structure, proven 48.5us) ----
// 256x256 block tile, 8 waves (4m x 2n) of 64x128. Grid 256, XCD-swizzled.
// LDS per buffer (64KB): [P: kh_l*8KB + fb_l*1KB] [A: +32KB, same]; x2 dbuf.
// Wave w stages fb_l=w for both P and A (2 gload_lds per phase).
__global__ __launch_bounds__(512, 2) void mfma_gemm_argmax(const unsigned short* __restrict__ Pf,
                                                           const unsigned short* __restrict__ Af,
                                                           const float* __restrict__ sums,
                                                           u64* __restrict__ packed,
                                                           unsigned int* __restrict__ done,
                                                           float* __restrict__ out) {
    __shared__ __align__(16) unsigned int lds[32768];  // 128 KB, 2 x 64KB buffers
    __shared__ unsigned int lastflag;
    __shared__ int cnt[8];

    const int bid = blockIdx.x;
    const int xcd = bid & 7;
    const int slt = bid >> 3;                       // 0..31
    const int rblk = (xcd >> 1) * 4 + (slt >> 3);   // 0..15
    const int cblk = (xcd & 1) * 8 + (slt & 7);     // 0..15
    const int r0 = rblk * 256;
    const int c0 = cblk * 256;

    const int wave = threadIdx.x >> 6;  // 0..7
    const int lane = threadIdx.x & 63;
    const int l31 = lane & 31;
    const int lh = lane >> 5;
    const int wm = wave & 3;   // m-quarter: rows wm*64..+63
    const int wn = wave >> 2;  // n-half:    cols wn*128..+127

    // per-wave global stage pointers: wave stages frag-block fb_l = wave
    const char* gPs = (const char*)Pf + (((size_t)(rblk * 8 + wave)) << 16) + (size_t)lane * 16;
    const char* gAs = (const char*)Af + (((size_t)(cblk * 8 + wave)) << 16) + (size_t)lane * 16;

    f32x16 zero16 = {0.f,0.f,0.f,0.f,0.f,0.f,0.f,0.f,0.f,0.f,0.f,0.f,0.f,0.f,0.f,0.f};
    f32x16 acc[2][4];
#pragma unroll
    for (int i = 0; i < 2; ++i)
#pragma unroll
        for (int j = 0; j < 4; ++j) acc[i][j] = zero16;

    // ---- prologue: stage tile 0 into buffer 0 (8 loads per wave) ----
#pragma unroll
    for (int kh_l = 0; kh_l < 4; ++kh_l) {
        __builtin_amdgcn_global_load_lds((const u32*)(gPs + ((size_t)kh_l << 10)),
                                         &lds[kh_l * 2048 + wave * 256], 16, 0, 0);
        __builtin_amdgcn_global_load_lds((const u32*)(gAs + ((size_t)kh_l << 10)),
                                         &lds[8192 + kh_l * 2048 + wave * 256], 16, 0, 0);
    }

    // ---- K loop: 16 tiles of BK=64 (4 kh phases each) ----
    for (int t = 0; t < 16; ++t) {
        const int cb = t & 1;
        const int nbuf = (cb ^ 1) * 16384;
        const int cbuf = cb * 16384;

        // tile-t data landed everywhere (my 8 loads issued one full tile ago)
        asm volatile("s_waitcnt vmcnt(0)" ::: "memory");
        __builtin_amdgcn_s_barrier();
        __builtin_amdgcn_sched_barrier(0);

#pragma unroll
        for (int kh_l = 0; kh_l < 4; ++kh_l) {
            // ds_read this phase's 6 fragments (linear, conflict-free)
            const u32* bp = &lds[cbuf + kh_l * 2048 + (wm * 2) * 256 + lane * 4];
            bf16x8 f_p0 = *(const bf16x8*)(bp);
            bf16x8 f_p1 = *(const bf16x8*)(bp + 256);
            const u32* ba = &lds[cbuf + 8192 + kh_l * 2048 + (wn * 4) * 256 + lane * 4];
            bf16x8 f_a0 = *(const bf16x8*)(ba);
            bf16x8 f_a1 = *(const bf16x8*)(ba + 256);
            bf16x8 f_a2 = *(const bf16x8*)(ba + 512);
            bf16x8 f_a3 = *(const bf16x8*)(ba + 768);

            // issue 2 stage loads of tile t+1 (land by next tile's vmcnt)
            if (t + 1 < 16) {
                const size_t go = ((size_t)((t + 1) * 4 + kh_l)) << 10;
                __builtin_amdgcn_global_load_lds((const u32*)(gPs + go),
                                                 &lds[nbuf + kh_l * 2048 + wave * 256], 16, 0, 0);
                __builtin_amdgcn_global_load_lds((const u32*)(gAs + go),
                                                 &lds[nbuf + 8192 + kh_l * 2048 + wave * 256], 16, 0, 0);
            }

            __builtin_amdgcn_s_barrier();
            asm volatile("s_waitcnt lgkmcnt(0)" ::: "memory");
            __builtin_amdgcn_sched_barrier(0);
            __builtin_amdgcn_s_setprio(1);
            acc[0][0] = __builtin_amdgcn_mfma_f32_32x32x16_bf16(f_p0, f_a0, acc[0][0], 0, 0, 0);
            acc[0][1] = __builtin_amdgcn_mfma_f32_32x32x16_bf16(f_p0, f_a1, acc[0][1], 0, 0, 0);
            acc[0][2] = __builtin_amdgcn_mfma_f32_32x32x16_bf16(f_p0, f_a2, acc[0][2], 0, 0, 0);
            acc[0][3] = __builtin_amdgcn_mfma_f32_32x32x16_bf16(f_p0, f_a3, acc[0][3], 0, 0, 0);
            acc[1][0] = __builtin_amdgcn_mfma_f32_32x32x16_bf16(f_p1, f_a0, acc[1][0], 0, 0, 0);
            acc[1][1] = __builtin_amdgcn_mfma_f32_32x32x16_bf16(f_p1, f_a1, acc[1][1], 0, 0, 0);
            acc[1][2] = __builtin_amdgcn_mfma_f32_32x32x16_bf16(f_p1, f_a2, acc[1][2], 0, 0, 0);
            acc[1][3] = __builtin_amdgcn_mfma_f32_32x32x16_bf16(f_p1, f_a3, acc[1][3], 0, 0, 0);
            __builtin_amdgcn_s_setprio(0);
            __builtin_amdgcn_s_barrier();
        }
    }

    // ---- epilogue: ian = 1/sqrt(sum), packed argmax ----
    float ian[4];
#pragma unroll
    for (int nt = 0; nt < 4; ++nt) ian[nt] = 1.0f / sqrtf(sums[c0 + wn * 128 + nt * 32 + l31]);

    // 32x32 C/D layout (m74/m101): col = lane&31, row = (reg&3)+8*(reg>>2)+4*(lane>>5)
#pragma unroll
    for (int mt = 0; mt < 2; ++mt)
#pragma unroll
        for (int reg = 0; reg < 16; ++reg) {
            const int row = r0 + wm * 64 + mt * 32 + (reg & 3) + 8 * (reg >> 2) + 4 * lh;
            u64 best = 0ULL;
#pragma unroll
            for (int nt = 0; nt < 4; ++nt) {
                const int col = c0 + wn * 128 + nt * 32 + l31;
                const float v = acc[mt][nt][reg] * ian[nt];
                const u64 p = ((u64)fkey(v) << 32) | (unsigned int)(~col);
                best = best > p ? best : p;
            }
#pragma unroll
            for (int m = 1; m <= 16; m <<= 1) {
                const u64 o = shfl_xor_u64(best, m);
                best = best > o ? best : o;
            }
            if (l31 == 0) atomicMax(&packed[row], best);
        }

    // ---- fused finalize: last block counts and writes out ----
    __syncthreads();
    if (threadIdx.x == 0) {
        __threadfence();  // publish this block's atomicMax results
        unsigned int old = atomicAdd(done, 1u);
        lastflag = (old == 255u) ? 1u : 0u;
    }
    __syncthreads();
    if (lastflag) {
        int c = 0;
        for (int r = threadIdx.x; r < NROWS; r += 512) {
            u64 v = atomicAdd(&packed[r], 0ULL);  // device-coherent read
            unsigned int col = ~(unsigned int)(v & 0xFFFFFFFFULL);
            c += (col == (unsigned int)r) ? 1 : 0;
        }
#pragma unroll
        for (int off = 32; off > 0; off >>= 1) c += __shfl_down(c, off, 64);
        if ((threadIdx.x & 63) == 0) cnt[threadIdx.x >> 6] = c;
        __syncthreads();
        if (threadIdx.x == 0) {
            int tot = 0;
#pragma unroll
            for (int w = 0; w < 8; ++w) tot += cnt[w];
            out[0] = 1.0f;  // exp(temploss - stop_gradient(temploss)) == 1 exactly
            out[1] = 100.0f * (float)tot / (float)NROWS;
        }
    }
}

// ---------------- fallback fp32 path (proven R1) ----------------
__global__ __launch_bounds__(256) void norms_kernel(const float* __restrict__ x,
                                                    float* __restrict__ inv_an,
                                                    u64* __restrict__ packed) {
    int gid  = blockIdx.x * 256 + threadIdx.x;
    int j    = gid >> 6;
    int lane = threadIdx.x & 63;
    if (gid < NROWS) packed[gid] = 0ULL;
    const float4* a = (const float4*)(x + (size_t)j * XSTR + DDIM);
    float s = 0.0f;
#pragma unroll
    for (int i = 0; i < 4; ++i) {
        float4 v = a[lane + i * 64];
        s += v.x * v.x + v.y * v.y + v.z * v.z + v.w * v.w;
    }
#pragma unroll
    for (int off = 32; off > 0; off >>= 1) s += __shfl_down(s, off, 64);
    if (lane == 0) inv_an[j] = 1.0f / sqrtf(s);
}

__global__ __launch_bounds__(256) void gemm_argmax_kernel(const float* __restrict__ x,
                                                          const float* __restrict__ inv_an,
                                                          u64* __restrict__ packed) {
    __shared__ __align__(16) float Pt[16][128];
    __shared__ __align__(16) float At[16][128];
    const int r0 = blockIdx.x * 128;
    const int c0 = blockIdx.y * 128;
    const int t = threadIdx.x;
    const int tx = t & 15;
    const int ty = t >> 4;
    const int srow = t >> 1;
    const int skq = (t & 1) * 8;
    float acc[8][8];
#pragma unroll
    for (int r = 0; r < 8; ++r)
#pragma unroll
        for (int c = 0; c < 8; ++c) acc[r][c] = 0.0f;
    const float* gp = x + (size_t)(r0 + srow) * XSTR + skq;
    const float* ga = x + (size_t)(c0 + srow) * XSTR + DDIM + skq;
    for (int k0 = 0; k0 < DDIM; k0 += 16) {
        __syncthreads();
        float4 p0 = *(const float4*)(gp + k0);
        float4 p1 = *(const float4*)(gp + k0 + 4);
        float4 a0 = *(const float4*)(ga + k0);
        float4 a1 = *(const float4*)(ga + k0 + 4);
        Pt[skq + 0][srow] = p0.x; Pt[skq + 1][srow] = p0.y;
        Pt[skq + 2][srow] = p0.z; Pt[skq + 3][srow] = p0.w;
        Pt[skq + 4][srow] = p1.x; Pt[skq + 5][srow] = p1.y;
        Pt[skq + 6][srow] = p1.z; Pt[skq + 7][srow] = p1.w;
        At[skq + 0][srow] = a0.x; At[skq + 1][srow] = a0.y;
        At[skq + 2][srow] = a0.z; At[skq + 3][srow] = a0.w;
        At[skq + 4][srow] = a1.x; At[skq + 5][srow] = a1.y;
        At[skq + 6][srow] = a1.z; At[skq + 7][srow] = a1.w;
        __syncthreads();
#pragma unroll
        for (int kk = 0; kk < 16; ++kk) {
            float pr[8], ar[8];
            *(float4*)&pr[0] = *(const float4*)&Pt[kk][ty * 8];
            *(float4*)&pr[4] = *(const float4*)&Pt[kk][ty * 8 + 4];
            *(float4*)&ar[0] = *(const float4*)&At[kk][tx * 8];
            *(float4*)&ar[4] = *(const float4*)&At[kk][tx * 8 + 4];
#pragma unroll
            for (int r = 0; r < 8; ++r)
#pragma unroll
                for (int c = 0; c < 8; ++c) acc[r][c] += pr[r] * ar[c];
        }
    }
    float ian[8];
#pragma unroll
    for (int c = 0; c < 8; ++c) ian[c] = inv_an[c0 + tx * 8 + c];
#pragma unroll
    for (int r = 0; r < 8; ++r) {
        int row = r0 + ty * 8 + r;
        u64 best = 0ULL;
#pragma unroll
        for (int c = 0; c < 8; ++c) {
            int col = c0 + tx * 8 + c;
            float v = acc[r][c] * ian[c];
            u64 p = ((u64)fkey(v) << 32) | (unsigned int)(~col);
            best = best > p ? best : p;
        }
#pragma unroll
        for (int m = 1; m <= 8; m <<= 1) {
            u64 o = shfl_xor_u64(best, m);
            best = best > o ? best : o;
        }
        if (tx == 0) atomicMax(&packed[row], best);
    }
}

__global__ __launch_bounds__(256) void finalize_kernel(const u64* __restrict__ packed,
                                                       float* __restrict__ out) {
    __shared__ int cnt_s;
    int t = threadIdx.x;
    if (t == 0) cnt_s = 0;
    __syncthreads();
    int c = 0;
    for (int r = t; r < NROWS; r += 256) {
        unsigned int col = ~(unsigned int)(packed[r] & 0xFFFFFFFFULL);
        c += (col == (unsigned int)r) ? 1 : 0;
    }
#pragma unroll
    for (int off = 32; off > 0; off >>= 1) c += __shfl_down(c, off, 64);
    if ((t & 63) == 0) atomicAdd(&cnt_s, c);
    __syncthreads();
    if (t == 0) {
        out[0] = 1.0f;
        out[1] = 100.0f * (float)cnt_s / (float)NROWS;
    }
}

extern "C" void kernel_launch(void* const* d_in, const int* in_sizes, int n_in,
                              void* d_out, int out_size, void* d_ws, size_t ws_size,
                              hipStream_t stream) {
    (void)in_sizes; (void)n_in; (void)out_size;
    const float* x = (const float*)d_in[0];
    float* out = (float*)d_out;

    if (ws_size >= (size_t)WS_NEED) {
        char* ws = (char*)d_ws;
        unsigned short* Pf = (unsigned short*)(ws + PF_OFF);
        unsigned short* Af = (unsigned short*)(ws + AF_OFF);
        float* sums = (float*)(ws + SUM_OFF);
        u64* packed = (u64*)(ws + PCK_OFF);
        unsigned int* done = (unsigned int*)(ws + DONE_OFF);

        hipMemsetAsync(ws + SUM_OFF, 0, (size_t)ZERO_BYTES, stream);
        conv_kernel<<<2048, 256, 0, stream>>>(x, Pf, Af, sums);
        mfma_gemm_argmax<<<256, 512, 0, stream>>>(Pf, Af, sums, packed, done, out);
    } else {
        float* inv_an = (float*)d_ws;
        u64* packed = (u64*)((char*)d_ws + NROWS * sizeof(float));
        norms_kernel<<<NROWS / 4, 256, 0, stream>>>(x, inv_an, packed);
        dim3 grid(NROWS / 128, NROWS / 128);
        gemm_argmax_kernel<<<grid, 256, 0, stream>>>(x, inv_an, packed);
        finalize_kernel<<<1, 256, 0, stream>>>(packed, out);
    }
}